// Round 1
// baseline (517.614 us; speedup 1.0000x reference)
//
#include <hip/hip_runtime.h>
#include <math.h>

#define N_OPS 320
#define RPC 16                  // rows per chunk
#define NCHUNK 4                // 4 * 16 = 64 rows per block
#define F4_PER_CHUNK 952        // RPC * 34 * 7 / 4 float4s

__global__ __launch_bounds__(256) void mahjong_kernel(
    const float* __restrict__ meta,        // (N,6)
    const float* __restrict__ wall,        // (N,34,5)
    const float* __restrict__ tile_prep,   // (N,320,34,7)
    const float* __restrict__ fan_prep,    // (N,320,80)
    const float* __restrict__ redundant,   // (N,320,34)
    const float* __restrict__ W_throw,     // (11)
    const float* __restrict__ b_throw,     // (1)
    const float* __restrict__ fan_coeff,   // (80)
    const float* __restrict__ fan_mult,    // (80)
    const float* __restrict__ tile_coeff,  // (34)
    float* __restrict__ out_max,           // (N,5)
    float* __restrict__ out_weighted,      // (N,34)
    int n)
{
    const int blk  = blockIdx.x;
    const int b    = blk / 5;
    const int g    = blk % 5;
    const int tid  = threadIdx.x;
    const int wave = tid >> 6;
    const int lane = tid & 63;

    // LDS ~17.8 KB -> 8 blocks/CU (32 waves, full occupancy)
    __shared__ float4 stage4[F4_PER_CHUNK];   // 15232 B: raw tile_prep chunk, coalesced f4 staged
    __shared__ float  qp_sm[RPC * 20];        // 1280 B: fan quad-partials (linear, conflict-free)
    __shared__ float  prob_sm[34];
    __shared__ float  fc_sm[80];
    __shared__ float  final_sm[64];
    __shared__ float  acc_sm[4][34];

    // ---- stage 0: prob_throw (Linear(11,1)) and fused fan coeff ----
    if (tid < 34) {
        float acc = b_throw[0];
        #pragma unroll
        for (int j = 0; j < 6; ++j) acc += meta[(size_t)b * 6 + j] * W_throw[j];
        const float* w = wall + ((size_t)b * 34 + tid) * 5;
        #pragma unroll
        for (int j = 0; j < 5; ++j) acc += w[j] * W_throw[6 + j];
        prob_sm[tid] = acc;
    }
    if (tid >= 64 && tid < 144) {
        int f = tid - 64;
        fc_sm[f] = fan_coeff[f] * fan_mult[f];
    }
    __syncthreads();

    // row-group decomposition: 16 threads per row, 16 rows per chunk
    const int r = tid >> 4;                    // row within chunk (0..15)
    const int p = tid & 15;                    // partner within row
    const int tcount = (p < 2) ? 3 : 2;        // 34 tiles = 2*3 + 14*2
    const int t0     = (p < 2) ? 3 * p : 2 * p + 2;

    const size_t rowB = (size_t)b * N_OPS + g * 64;

    for (int c = 0; c < NCHUNK; ++c) {
        const size_t row0 = rowB + c * RPC;

        // ---- coalesced float4 staging of tile_prep chunk (each HBM line touched once) ----
        // row0 is a multiple of 16 -> row0*238 floats is 16B-aligned
        const float4* src4 = (const float4*)(tile_prep + row0 * 238);
        #pragma unroll
        for (int k = 0; k < 3; ++k) stage4[tid + 256 * k] = src4[tid + 256 * k];
        if (tid < F4_PER_CHUNK - 768) stage4[tid + 768] = src4[tid + 768];

        // ---- fan quad-partials: coalesced float4, reduce 4 -> 1 immediately ----
        {
            const float4* fsrc = (const float4*)(fan_prep + row0 * 80);
            float4 v = fsrc[tid];
            int f = 4 * (tid % 20);
            qp_sm[tid] = v.x * fc_sm[f]     + v.y * fc_sm[f + 1]
                       + v.z * fc_sm[f + 2] + v.w * fc_sm[f + 3];
            if (tid < RPC * 20 - 256) {        // tail: 64 more
                int i = 256 + tid;
                float4 u = fsrc[i];
                int f2 = 4 * (i % 20);
                qp_sm[i] = u.x * fc_sm[f2]     + u.y * fc_sm[f2 + 1]
                         + u.z * fc_sm[f2 + 2] + u.w * fc_sm[f2 + 3];
            }
        }
        __syncthreads();

        // ---- terms from LDS + per-row product/fansum via 16-lane shuffle tree ----
        const float* srow = (const float*)stage4 + r * 238;
        float prod = 1.0f;
        for (int ti = 0; ti < tcount; ++ti) {
            const int t = t0 + ti;
            const float* e = srow + 7 * t;
            float c0 = e[0], c1 = e[1], c2 = e[2], c3 = e[3];
            float c4 = e[4], c5 = e[5], c6 = e[6];
            // prob>0 by construction; tile_hidden_ct in [0.5,1.5] -> no inf/nan
            prod *= c0 * exp2f(c1 * log2f(prob_sm[t])) + c6 + (c3 * c2 / c4) * c5;
        }
        const float* qr = qp_sm + r * 20;
        float qs = (p < 4) ? (qr[2 * p] + qr[2 * p + 1]) : qr[4 + p];  // 20 = 4*2 + 12*1
        #pragma unroll
        for (int sh = 1; sh < 16; sh <<= 1) {
            prod *= __shfl_xor(prod, sh);
            qs   += __shfl_xor(qs, sh);
        }
        if (p == 0) final_sm[c * RPC + r] = prod * 100.0f * qs;
        __syncthreads();   // final_sm visible; stage4/qp_sm safe to overwrite next chunk
    }

    // ---- stage 3: tile_bound_winrate partials; wave w covers rows 16w..16w+15 ----
    if (lane < 34) {
        const float* rr = redundant + (rowB + wave * 16) * 34;
        float acc3 = 0.0f;
        #pragma unroll
        for (int i = 0; i < 16; ++i)
            acc3 += rr[i * 34 + lane] * final_sm[wave * 16 + i];
        acc_sm[wave][lane] = acc3;
    }
    __syncthreads();

    // ---- outputs (wave 0 only) ----
    if (wave == 0) {
        float tbw = 0.0f;
        if (lane < 34)
            tbw = acc_sm[0][lane] + acc_sm[1][lane] + acc_sm[2][lane] + acc_sm[3][lane];
        if (g == 0) {
            if (lane < 34)
                out_weighted[(size_t)b * 34 + lane] = tbw * tile_coeff[lane];
            float fs = final_sm[lane];             // all 64 rows live in final_sm
            #pragma unroll
            for (int sh = 1; sh < 64; sh <<= 1) fs += __shfl_xor(fs, sh);
            if (lane == 0) out_max[(size_t)b * 5] = fs;
        } else {
            float m = (lane < 34) ? tbw : -INFINITY;
            #pragma unroll
            for (int sh = 1; sh < 64; sh <<= 1) m = fmaxf(m, __shfl_xor(m, sh));
            if (lane == 0) out_max[(size_t)b * 5 + g] = m;
        }
    }
}

extern "C" void kernel_launch(void* const* d_in, const int* in_sizes, int n_in,
                              void* d_out, int out_size, void* d_ws, size_t ws_size,
                              hipStream_t stream) {
    const float* meta       = (const float*)d_in[0];
    const float* wall       = (const float*)d_in[1];
    const float* tile_prep  = (const float*)d_in[2];
    const float* fan_prep   = (const float*)d_in[3];
    const float* redundant  = (const float*)d_in[4];
    // d_in[5] count_prep, d_in[6] chi_peng_count_remain: unused by reference
    const float* W_throw    = (const float*)d_in[7];
    const float* b_throw    = (const float*)d_in[8];
    const float* fan_coeff  = (const float*)d_in[9];
    const float* fan_mult   = (const float*)d_in[10];
    const float* tile_coeff = (const float*)d_in[11];

    int n = in_sizes[0] / 6;
    float* out_max      = (float*)d_out;            // (n,5)
    float* out_weighted = out_max + (size_t)n * 5;  // (n,34)

    dim3 grid(n * 5), block(256);
    hipLaunchKernelGGL(mahjong_kernel, grid, block, 0, stream,
                       meta, wall, tile_prep, fan_prep, redundant,
                       W_throw, b_throw, fan_coeff, fan_mult, tile_coeff,
                       out_max, out_weighted, n);
}

// Round 3
// 513.197 us; speedup vs baseline: 1.0086x; 1.0086x over previous
//
#include <hip/hip_runtime.h>
#include <math.h>

#define N_OPS 320

__global__ __launch_bounds__(256) void mahjong_kernel(
    const float* __restrict__ meta,        // (N,6)
    const float* __restrict__ wall,        // (N,34,5)
    const float* __restrict__ tile_prep,   // (N,320,34,7)
    const float* __restrict__ fan_prep,    // (N,320,80)
    const float* __restrict__ redundant,   // (N,320,34)
    const float* __restrict__ W_throw,     // (11)
    const float* __restrict__ b_throw,     // (1)
    const float* __restrict__ fan_coeff,   // (80)
    const float* __restrict__ fan_mult,    // (80)
    const float* __restrict__ tile_coeff,  // (34)
    float* __restrict__ out_max,           // (N,5)
    float* __restrict__ out_weighted,      // (N,34)
    int n)
{
    const int blk = blockIdx.x;
    const int b   = blk / 5;
    const int g   = blk % 5;
    const int tid = threadIdx.x;
    const int w   = tid >> 6;     // wave 0..3, owns 16 rows
    const int l   = tid & 63;     // lane
    const int h   = l >> 5;       // row half within chunk (2 rows/chunk)
    const int q   = l & 31;       // position within half

    // LDS ~8.6 KB -> occupancy not LDS-limited
    __shared__ float4 stage[4][119];   // per-WAVE private: 2 rows x 238 floats
    __shared__ float  lp_sm[34];       // log2(prob_throw), hoisted
    __shared__ float  fc_sm[80];
    __shared__ float  acc_sm[4][34];
    __shared__ float  fsum_sm[4];

    // ---- prologue: prob_throw (Linear(11,1)) -> log2, fused fan coeff ----
    if (tid < 34) {
        float acc = b_throw[0];
        #pragma unroll
        for (int j = 0; j < 6; ++j) acc += meta[(size_t)b * 6 + j] * W_throw[j];
        const float* wl = wall + ((size_t)b * 34 + tid) * 5;
        #pragma unroll
        for (int j = 0; j < 5; ++j) acc += wl[j] * W_throw[6 + j];
        lp_sm[tid] = log2f(acc);       // prob > 0 by construction
    }
    if (tid >= 64 && tid < 144) {
        int f = tid - 64;
        fc_sm[f] = fan_coeff[f] * fan_mult[f];
    }
    __syncthreads();                   // barrier #1 (last until output combine)

    const size_t rowB = (size_t)b * N_OPS + g * 64 + w * 16;  // wave's first row
    const float4* fan4 = (const float4*)fan_prep;

    float acc3 = 0.0f;   // lane<34: partial tile_bound_winrate over this wave's rows
    float fsum = 0.0f;   // sum of fin over this wave's rows (g==0 path)

    // ---- prefetch chunk 0 into registers ----
    const float4* s4 = (const float4*)(tile_prep + rowB * 238);
    float4 a0 = s4[l];
    float4 a1 = (l < 55) ? s4[64 + l] : make_float4(0.f, 0.f, 0.f, 0.f);
    float4 fv = (q < 20) ? fan4[(rowB + h) * 20 + q] : make_float4(0.f, 0.f, 0.f, 0.f);
    float v0 = 0.f, v1 = 0.f;
    {
        const float* rr = redundant + rowB * 34;
        if (l < 34) { v0 = rr[l]; v1 = rr[34 + l]; }
    }

    // ---- main loop: 8 chunks x 2 rows, wave-autonomous, NO __syncthreads ----
    #pragma unroll
    for (int c = 0; c < 8; ++c) {
        // write current chunk to wave-private LDS (same-wave RAW: compiler-ordered)
        stage[w][l] = a0;
        if (l < 55) stage[w][64 + l] = a1;

        // issue next chunk's global loads; they fly during this chunk's compute
        float4 na0 = make_float4(0.f, 0.f, 0.f, 0.f);
        float4 na1 = na0, nfv = na0;
        float nv0 = 0.f, nv1 = 0.f;
        if (c < 7) {
            const size_t gr = rowB + 2 * (c + 1);
            const float4* n4 = (const float4*)(tile_prep + gr * 238);
            na0 = n4[l];
            if (l < 55) na1 = n4[64 + l];
            if (q < 20) nfv = fan4[(gr + h) * 20 + q];
            const float* rr = redundant + gr * 34;
            if (l < 34) { nv0 = rr[l]; nv1 = rr[34 + l]; }
        }

        // fan partial for this lane (row h of the chunk)
        float qs = 0.0f;
        if (q < 20)
            qs = fv.x * fc_sm[4*q]   + fv.y * fc_sm[4*q+1]
               + fv.z * fc_sm[4*q+2] + fv.w * fc_sm[4*q+3];

        // terms: lane handles tile q of row h (lanes q<2 also tiles 32+q)
        // stride-7 float reads: 7q mod 32 is a bijection -> <=2-way aliasing (free)
        const float* srow = (const float*)&stage[w][0] + h * 238;
        const float* e = srow + 7 * q;
        float term = e[0] * exp2f(e[1] * lp_sm[q]) + e[6] + (e[3] * e[2] / e[4]) * e[5];
        if (q < 2) {
            const int t2 = 32 + q;
            const float* e2 = srow + 7 * t2;
            term *= e2[0] * exp2f(e2[1] * lp_sm[t2]) + e2[6] + (e2[3] * e2[2] / e2[4]) * e2[5];
        }

        // per-row (per-half) product & fan-sum: xor masks 1..16 stay inside halves
        #pragma unroll
        for (int sh = 1; sh < 32; sh <<= 1) {
            term *= __shfl_xor(term, sh);
            qs   += __shfl_xor(qs, sh);
        }
        float fin  = term * 100.0f * qs;   // each half holds its own row's value
        float fin0 = __shfl(fin, 0);       // row 2c
        float fin1 = __shfl(fin, 32);      // row 2c+1

        acc3 += v0 * fin0 + v1 * fin1;     // lanes >=34 hold v=0
        fsum += fin0 + fin1;

        a0 = na0; a1 = na1; fv = nfv; v0 = nv0; v1 = nv1;
    }

    if (l < 34) acc_sm[w][l] = acc3;
    if (l == 0) fsum_sm[w] = fsum;
    __syncthreads();                       // barrier #2

    // ---- outputs (wave 0 only) ----
    if (w == 0) {
        float tbw = 0.0f;
        if (l < 34)
            tbw = acc_sm[0][l] + acc_sm[1][l] + acc_sm[2][l] + acc_sm[3][l];
        if (g == 0) {
            if (l < 34)
                out_weighted[(size_t)b * 34 + l] = tbw * tile_coeff[l];
            if (l == 0)
                out_max[(size_t)b * 5] = fsum_sm[0] + fsum_sm[1] + fsum_sm[2] + fsum_sm[3];
        } else {
            float m = (l < 34) ? tbw : -INFINITY;
            #pragma unroll
            for (int sh = 1; sh < 64; sh <<= 1) m = fmaxf(m, __shfl_xor(m, sh));
            if (l == 0) out_max[(size_t)b * 5 + g] = m;
        }
    }
}

extern "C" void kernel_launch(void* const* d_in, const int* in_sizes, int n_in,
                              void* d_out, int out_size, void* d_ws, size_t ws_size,
                              hipStream_t stream) {
    const float* meta       = (const float*)d_in[0];
    const float* wall       = (const float*)d_in[1];
    const float* tile_prep  = (const float*)d_in[2];
    const float* fan_prep   = (const float*)d_in[3];
    const float* redundant  = (const float*)d_in[4];
    // d_in[5] count_prep, d_in[6] chi_peng_count_remain: unused by reference
    const float* W_throw    = (const float*)d_in[7];
    const float* b_throw    = (const float*)d_in[8];
    const float* fan_coeff  = (const float*)d_in[9];
    const float* fan_mult   = (const float*)d_in[10];
    const float* tile_coeff = (const float*)d_in[11];

    int n = in_sizes[0] / 6;
    float* out_max      = (float*)d_out;            // (n,5)
    float* out_weighted = out_max + (size_t)n * 5;  // (n,34)

    dim3 grid(n * 5), block(256);
    hipLaunchKernelGGL(mahjong_kernel, grid, block, 0, stream,
                       meta, wall, tile_prep, fan_prep, redundant,
                       W_throw, b_throw, fan_coeff, fan_mult, tile_coeff,
                       out_max, out_weighted, n);
}